// Round 10
// baseline (460.887 us; speedup 1.0000x reference)
//
#include <hip/hip_runtime.h>
#include <hip/hip_bf16.h>

#define N_NODES 50000
#define N_PAD   50176    // padded rows for GEMM staging (multiple of 128)
#define N_EDGES 800000
#define IN_FEAT 256
#define HEADS 8
#define D_K 64
#define HD 512  // HEADS*D_K

typedef __hip_bfloat16 bf16;
typedef unsigned int u32;

using bf16x8 = __attribute__((ext_vector_type(8))) short;
using f32x4  = __attribute__((ext_vector_type(4))) float;

// ---------------- workspace layout (bytes) ----------------
#define WS_Q       0
#define WS_K       51200000
#define WS_V       102400000
#define WS_OFFSETS 153600000
#define WS_CURSOR  153800192
#define WS_DEG     154000192
#define WS_CSR     154200192
#define WS_SQ2     157400192
#define WS_AUX     159000192   // int[64] scan partials

// d_out used as scratch before edge_attn overwrites it entirely:
#define DOUT_XB 0
#define DOUT_WT 25690112

#define SCAN_BLOCKS 49   // ceil(50000/1024)

__device__ __forceinline__ float bflo(u32 u) { return __uint_as_float(u << 16); }
__device__ __forceinline__ float bfhi(u32 u) { return __uint_as_float(u & 0xffff0000u); }

__device__ __forceinline__ void gload16(const void* g, void* l)
{
    __builtin_amdgcn_global_load_lds(
        (const __attribute__((address_space(1))) unsigned int*)g,
        (__attribute__((address_space(3))) unsigned int*)l,
        16, 0, 0);
}

// ---------------- input conversion ----------------
__global__ __launch_bounds__(256) void convert_x(
    const float* __restrict__ x, bf16* __restrict__ xb)
{
    const int t   = blockIdx.x * 256 + threadIdx.x;
    const int row = t >> 5;
    const int c8  = (t & 31) * 8;
    if (row >= N_PAD) return;
    alignas(16) bf16 tmp[8];
    if (row < N_NODES) {
        const float* p = x + (size_t)row * IN_FEAT + c8;
        float4 a = *(const float4*)p;
        float4 b = *(const float4*)(p + 4);
        tmp[0] = __float2bfloat16(a.x); tmp[1] = __float2bfloat16(a.y);
        tmp[2] = __float2bfloat16(a.z); tmp[3] = __float2bfloat16(a.w);
        tmp[4] = __float2bfloat16(b.x); tmp[5] = __float2bfloat16(b.y);
        tmp[6] = __float2bfloat16(b.z); tmp[7] = __float2bfloat16(b.w);
    } else {
#pragma unroll
        for (int i = 0; i < 8; ++i) tmp[i] = __float2bfloat16(0.f);
    }
    *(uint4*)(xb + (size_t)row * IN_FEAT + c8) = *(const uint4*)tmp;
}

__global__ __launch_bounds__(256) void convert_w(
    const float* __restrict__ Wq, const float* __restrict__ Wk, const float* __restrict__ Wv,
    bf16* __restrict__ Wt)
{
    const int t = blockIdx.x * 256 + threadIdx.x;
    if (t >= 3 * 512 * 256) return;
    const int mat = t >> 17;
    const int r   = t & 131071;
    const int n   = r >> 8;
    const int k   = r & 255;
    const float* W = (mat == 0) ? Wq : (mat == 1) ? Wk : Wv;
    Wt[t] = __float2bfloat16(W[k * HD + n]);
}

// ---------------- MFMA bf16 QKV GEMM: double-buffered pipeline ----------------
__global__ __launch_bounds__(256) void mfma_qkv(
    const bf16* __restrict__ xb, const bf16* __restrict__ Wt,
    bf16* __restrict__ Qb, bf16* __restrict__ Kb, bf16* __restrict__ Vb)
{
    __shared__ uint4 lds4[2048];   // 32 KiB: [buf][A 8K | B 8K]
    char* lds = (char*)lds4;

    const int tid  = threadIdx.x;
    const int lane = tid & 63;
    const int wid  = tid >> 6;
    const int wr   = wid >> 1;
    const int wc   = wid & 1;

    const int m0  = blockIdx.x * 128;
    const int n0  = blockIdx.y * 128;
    const int mat = blockIdx.z;
    const bf16* __restrict__ wt = Wt + (size_t)mat * 512 * 256;
    bf16* __restrict__ outp = (mat == 0) ? Qb : (mat == 1) ? Kb : Vb;

    const int rch  = lane >> 2;
    const int slot = (lane & 3) ^ (rch & 3);
    const int sc0  = wid;
    const int sc1  = wid + 4;
    const size_t arow0 = (size_t)(m0 + sc0 * 16 + rch) * IN_FEAT + slot * 8;
    const size_t arow1 = (size_t)(m0 + sc1 * 16 + rch) * IN_FEAT + slot * 8;
    const size_t brow0 = (size_t)(n0 + sc0 * 16 + rch) * IN_FEAT + slot * 8;
    const size_t brow1 = (size_t)(n0 + sc1 * 16 + rch) * IN_FEAT + slot * 8;

    const int fr    = lane & 15;
    const int fslot = (((lane >> 4) ^ (lane & 3)) << 4);
    const int abase = (wr * 64 + fr) * 64 + fslot;
    const int bbase = (wc * 64 + fr) * 64 + fslot;

    f32x4 acc[4][4];
#pragma unroll
    for (int i = 0; i < 4; ++i)
#pragma unroll
        for (int j = 0; j < 4; ++j) acc[i][j] = {0.f, 0.f, 0.f, 0.f};

#define STAGE(t, buf) do {                                              \
        gload16(xb + arow0 + (t) * 32, lds + (buf) * 16384 + sc0 * 1024);          \
        gload16(xb + arow1 + (t) * 32, lds + (buf) * 16384 + sc1 * 1024);          \
        gload16(wt + brow0 + (t) * 32, lds + (buf) * 16384 + 8192 + sc0 * 1024);   \
        gload16(wt + brow1 + (t) * 32, lds + (buf) * 16384 + 8192 + sc1 * 1024);   \
    } while (0)

    STAGE(0, 0);
#pragma unroll
    for (int t = 0; t < 8; ++t) {
        const int cur = t & 1;
        if (t < 7) {
            STAGE(t + 1, cur ^ 1);
            asm volatile("s_waitcnt vmcnt(4)" ::: "memory");   // tile t landed (mine)
        } else {
            asm volatile("s_waitcnt vmcnt(0)" ::: "memory");
        }
        __builtin_amdgcn_s_barrier();                          // tile t landed (all waves)

        const char* A = lds + cur * 16384;
        const char* B = A + 8192;
        bf16x8 aF[4], bF[4];
#pragma unroll
        for (int m = 0; m < 4; ++m) aF[m] = *(const bf16x8*)(A + abase + m * 1024);
#pragma unroll
        for (int n = 0; n < 4; ++n) bF[n] = *(const bf16x8*)(B + bbase + n * 1024);
#pragma unroll
        for (int m = 0; m < 4; ++m)
#pragma unroll
            for (int n = 0; n < 4; ++n)
                acc[m][n] = __builtin_amdgcn_mfma_f32_16x16x32_bf16(aF[m], bF[n], acc[m][n], 0, 0, 0);
        __builtin_amdgcn_s_barrier();                          // reads done before overwrite
    }
#undef STAGE

    const int c_col = lane & 15;
    const int r_hi  = (lane >> 4) * 4;
#pragma unroll
    for (int m = 0; m < 4; ++m) {
        const int grow_base = m0 + wr * 64 + m * 16 + r_hi;
#pragma unroll
        for (int j = 0; j < 4; ++j) {
            const int grow = grow_base + j;
            if (grow < N_NODES) {
#pragma unroll
                for (int n = 0; n < 4; ++n)
                    outp[(size_t)grow * HD + n0 + wc * 64 + n * 16 + c_col] =
                        __float2bfloat16(acc[m][n][j]);
            }
        }
    }
}

// ---------------- CSR build ----------------
__global__ void hist_kernel(const int* __restrict__ row, int* __restrict__ deg)
{
    int e = blockIdx.x * 256 + threadIdx.x;
    if (e < N_EDGES) atomicAdd(&deg[row[e]], 1);
}

__global__ __launch_bounds__(1024) void scan_local(const int* __restrict__ deg,
                                                   int* __restrict__ offsets,
                                                   int* __restrict__ aux)
{
    __shared__ int buf[1024];
    const int tid = threadIdx.x;
    const int i = blockIdx.x * 1024 + tid;
    const int v = (i < N_NODES) ? deg[i] : 0;
    buf[tid] = v;
    __syncthreads();
    for (int off = 1; off < 1024; off <<= 1) {
        int t = (tid >= off) ? buf[tid - off] : 0;
        __syncthreads();
        buf[tid] += t;
        __syncthreads();
    }
    if (i < N_NODES) offsets[i] = buf[tid] - v;
    if (tid == 1023) aux[blockIdx.x] = buf[1023];
}

__global__ void scan_aux(int* __restrict__ aux)
{
    const int tid = threadIdx.x;
    const int orig = (tid < SCAN_BLOCKS) ? aux[tid] : 0;
    int v = orig;
    for (int off = 1; off < 64; off <<= 1) {
        int t = __shfl_up(v, off, 64);
        if (tid >= off) v += t;
    }
    if (tid < SCAN_BLOCKS) aux[tid] = v - orig;
}

__global__ __launch_bounds__(1024) void scan_apply(const int* __restrict__ aux,
                                                   int* __restrict__ offsets,
                                                   int* __restrict__ cursor)
{
    const int i = blockIdx.x * 1024 + threadIdx.x;
    if (i < N_NODES) {
        const int off = offsets[i] + aux[i >> 10];
        offsets[i] = off;
        cursor[i]  = off;
    }
    if (i == 0) offsets[N_NODES] = N_EDGES;
}

__global__ void scatter_kernel(const int* __restrict__ row, const int* __restrict__ col,
                               int* __restrict__ cursor, int* __restrict__ csr_col)
{
    int e = blockIdx.x * 256 + threadIdx.x;
    if (e < N_EDGES) {
        const int pos = atomicAdd(&cursor[row[e]], 1);
        csr_col[pos] = col[e];
    }
}

// ---------------- sQ2 precompute ----------------
__global__ __launch_bounds__(256) void sq2_kernel(
    const bf16* __restrict__ Qb, const float* __restrict__ Dm, float* __restrict__ sQ2)
{
    const int lane = threadIdx.x & 63;
    const int wid  = threadIdx.x >> 6;
    const int n = blockIdx.x * 4 + wid;
    if (n >= N_NODES) return;

    uint4 qp = *(const uint4*)(Qb + (size_t)n * HD + lane * 8);
    float4 da = *(const float4*)(Dm + lane * 8);
    float4 db = *(const float4*)(Dm + lane * 8 + 4);
    float q0 = bflo(qp.x), q1 = bfhi(qp.x), q2 = bflo(qp.y), q3 = bfhi(qp.y);
    float q4 = bflo(qp.z), q5 = bfhi(qp.z), q6 = bflo(qp.w), q7 = bfhi(qp.w);
    float s = da.x*q0*q0 + da.y*q1*q1 + da.z*q2*q2 + da.w*q3*q3
            + db.x*q4*q4 + db.y*q5*q5 + db.z*q6*q6 + db.w*q7*q7;
    s += __shfl_xor(s, 1, 64);
    s += __shfl_xor(s, 2, 64);
    s += __shfl_xor(s, 4, 64);
    if ((lane & 7) == 0) sQ2[n * 8 + (lane >> 3)] = s;
}

// ---------------- fused edge phase: R9 direct-gather, 2 waves/block ----------
// R9 hit the ~16 workgroup-slots/CU cap at 1 wave/block (43% occupancy, 60
// VGPR allows 32 waves/CU). 128-thread blocks (2 waves, one node each) keep
// the fine backfill granularity but double the wave ceiling: 16 wg x 2 = 32
// waves/CU. More waves = more misses in flight on the latency-bound gather.
__global__ __launch_bounds__(128) void edge_attn(
    const bf16* __restrict__ Qb, const bf16* __restrict__ Kb, const bf16* __restrict__ Vb,
    const float* __restrict__ Dm, const float* __restrict__ sQ2,
    const int* __restrict__ offsets, const int* __restrict__ csr_col,
    float* __restrict__ out)
{
    __shared__ float dk_lds[2][8][72];   // [wave][head][64 dims + pad] = 4.5 KiB

    const int lane = threadIdx.x & 63;
    const int wid  = threadIdx.x >> 6;   // 0..1
    const int r = blockIdx.x * 2 + wid;  // N_NODES = 50000 even, grid = 25000

    const int hB = lane >> 3;         // B-layout: head of dims [lane*8, +8)
    const int tB = lane & 7;
    const int hA = lane & 7;          // A-layout: head
    const int jA = lane >> 3;         // A-layout: edge slot

    const float4 da = *(const float4*)(Dm + lane * 8);
    const float4 db = *(const float4*)(Dm + lane * 8 + 4);

    // ---- node init: DK = D*K[r] into LDS (B-layout), sK2 per head ----
    uint4 kp = *(const uint4*)(Kb + (size_t)r * HD + lane * 8);
    const float k0 = bflo(kp.x), k1 = bfhi(kp.x), k2 = bflo(kp.y), k3 = bfhi(kp.y);
    const float k4 = bflo(kp.z), k5 = bfhi(kp.z), k6 = bflo(kp.w), k7 = bfhi(kp.w);
    const float e0 = da.x*k0, e1 = da.y*k1, e2 = da.z*k2, e3 = da.w*k3;
    const float e4 = db.x*k4, e5 = db.y*k5, e6 = db.z*k6, e7 = db.w*k7;
    float sk = e0*k0 + e1*k1 + e2*k2 + e3*k3 + e4*k4 + e5*k5 + e6*k6 + e7*k7;
    sk += __shfl_xor(sk, 1, 64);
    sk += __shfl_xor(sk, 2, 64);
    sk += __shfl_xor(sk, 4, 64);      // sK2 for head hB on every lane
    {
        float4 w0 = {e0, e1, e2, e3}, w1 = {e4, e5, e6, e7};
        *(float4*)&dk_lds[wid][hB][tB * 8]     = w0;
        *(float4*)&dk_lds[wid][hB][tB * 8 + 4] = w1;
    }
    const float skA = __shfl(sk, hA * 8, 64);   // sK2 for A-head

    const int s0 = offsets[r];
    const int s1 = offsets[r + 1];

    float m = -INFINITY, l = 0.f;
    float o0=0,o1=0,o2=0,o3=0,o4=0,o5=0,o6=0,o7=0;

    const float* dkrow = &dk_lds[wid][hA][0];

    for (int eb = s0; eb < s1; eb += 8) {
        const int cnt = min(8, s1 - eb);              // wave-uniform
        const int cj  = csr_col[eb + min(jA, cnt - 1)];

        // ---- phase A: per-lane direct Q loads + within-lane dot ----
        const bf16* qrow = Qb + (size_t)cj * HD + hA * D_K;
        float cross = 0.f;
#pragma unroll
        for (int t = 0; t < 8; ++t) {
            uint4 qp2 = *(const uint4*)(qrow + t * 8);
            float4 ka  = *(const float4*)(dkrow + t * 8);
            float4 kb2 = *(const float4*)(dkrow + t * 8 + 4);
            cross += ka.x * bflo(qp2.x) + ka.y * bfhi(qp2.x)
                   + ka.z * bflo(qp2.y) + ka.w * bfhi(qp2.y)
                   + kb2.x * bflo(qp2.z) + kb2.y * bfhi(qp2.z)
                   + kb2.z * bflo(qp2.w) + kb2.w * bfhi(qp2.w);
        }
        const float sq2v = sQ2[cj * 8 + hA];
        const float sraw = (cj == r) ? cross : (skA - 2.f * cross + sq2v);
        const float y = sraw * 0.125f;
        float s = fmaxf(y, 0.2f * y);                 // leaky_relu 0.2
        if (jA >= cnt) s = -INFINITY;

        // ---- batched online softmax ----
        float bm = s;
        bm = fmaxf(bm, __shfl_xor(bm, 8, 64));
        bm = fmaxf(bm, __shfl_xor(bm, 16, 64));
        bm = fmaxf(bm, __shfl_xor(bm, 32, 64));
        const float mn   = fmaxf(m, bm);
        const float corr = __expf(m - mn);            // exp(-inf)=0 on first pass
        const float w    = __expf(s - mn);
        m = mn;
        float ls = w;
        ls += __shfl_xor(ls, 8, 64);
        ls += __shfl_xor(ls, 16, 64);
        ls += __shfl_xor(ls, 32, 64);
        l = l * corr + ls;

        // ---- phase B: coalesced V accumulation ----
        const float corrB = __shfl(corr, hB, 64);
        o0*=corrB; o1*=corrB; o2*=corrB; o3*=corrB;
        o4*=corrB; o5*=corrB; o6*=corrB; o7*=corrB;
#pragma unroll
        for (int e = 0; e < 8; ++e) {
            if (e >= cnt) break;                      // wave-uniform
            const int   ce    = __shfl(cj, e * 8, 64);
            const float alpha = __shfl(w, e * 8 + hB, 64);
            uint4 vp = *(const uint4*)(Vb + (size_t)ce * HD + lane * 8);
            o0 = fmaf(alpha, bflo(vp.x), o0);
            o1 = fmaf(alpha, bfhi(vp.x), o1);
            o2 = fmaf(alpha, bflo(vp.y), o2);
            o3 = fmaf(alpha, bfhi(vp.y), o3);
            o4 = fmaf(alpha, bflo(vp.z), o4);
            o5 = fmaf(alpha, bfhi(vp.z), o5);
            o6 = fmaf(alpha, bflo(vp.w), o6);
            o7 = fmaf(alpha, bfhi(vp.w), o7);
        }
    }

    const float lB  = __shfl(l, hB, 64);
    const float inv = 1.f / (lB + 1e-16f);
    float4 r0 = {o0*inv, o1*inv, o2*inv, o3*inv};
    float4 r1 = {o4*inv, o5*inv, o6*inv, o7*inv};
    *(float4*)(out + (size_t)r * HD + lane * 8)     = r0;
    *(float4*)(out + (size_t)r * HD + lane * 8 + 4) = r1;
}

// ---------------- launcher ----------------
extern "C" void kernel_launch(void* const* d_in, const int* in_sizes, int n_in,
                              void* d_out, int out_size, void* d_ws, size_t ws_size,
                              hipStream_t stream)
{
    const float* x  = (const float*)d_in[0];
    const int*   ei = (const int*)d_in[1];
    const float* Wq = (const float*)d_in[2];
    const float* Wk = (const float*)d_in[3];
    const float* Wv = (const float*)d_in[4];
    const float* Dm = (const float*)d_in[5];
    float* out = (float*)d_out;

    char* ws = (char*)d_ws;
    bf16* Qb      = (bf16*)(ws + WS_Q);
    bf16* Kb      = (bf16*)(ws + WS_K);
    bf16* Vb      = (bf16*)(ws + WS_V);
    int*  offsets = (int*)(ws + WS_OFFSETS);
    int*  cursor  = (int*)(ws + WS_CURSOR);
    int*  deg     = (int*)(ws + WS_DEG);
    int*  csr_col = (int*)(ws + WS_CSR);
    float* sQ2    = (float*)(ws + WS_SQ2);
    int*  aux     = (int*)(ws + WS_AUX);

    bf16* xb = (bf16*)((char*)d_out + DOUT_XB);
    bf16* Wt = (bf16*)((char*)d_out + DOUT_WT);

    const int* row = ei;
    const int* col = ei + N_EDGES;

    hipMemsetAsync(deg, 0, N_NODES * sizeof(int), stream);
    hipLaunchKernelGGL(convert_x, dim3(N_PAD * 32 / 256), dim3(256), 0, stream, x, xb);
    hipLaunchKernelGGL(convert_w, dim3((3 * 512 * 256 + 255) / 256), dim3(256), 0, stream,
                       Wq, Wk, Wv, Wt);
    hipLaunchKernelGGL(hist_kernel, dim3((N_EDGES + 255) / 256), dim3(256), 0, stream, row, deg);
    hipLaunchKernelGGL(mfma_qkv, dim3(N_PAD / 128, 4, 3), dim3(256), 0, stream,
                       xb, Wt, Qb, Kb, Vb);
    hipLaunchKernelGGL(scan_local, dim3(SCAN_BLOCKS), dim3(1024), 0, stream, deg, offsets, aux);
    hipLaunchKernelGGL(scan_aux, dim3(1), dim3(64), 0, stream, aux);
    hipLaunchKernelGGL(scan_apply, dim3(SCAN_BLOCKS), dim3(1024), 0, stream, aux, offsets, cursor);
    hipLaunchKernelGGL(scatter_kernel, dim3((N_EDGES + 255) / 256), dim3(256), 0, stream,
                       row, col, cursor, csr_col);
    hipLaunchKernelGGL(sq2_kernel, dim3((N_NODES + 3) / 4), dim3(256), 0, stream, Qb, Dm, sQ2);
    hipLaunchKernelGGL(edge_attn, dim3(N_NODES / 2), dim3(128), 0, stream,
                       Qb, Kb, Vb, Dm, sQ2, offsets, csr_col, out);
}

// Round 11
// 441.547 us; speedup vs baseline: 1.0438x; 1.0438x over previous
//
#include <hip/hip_runtime.h>
#include <hip/hip_bf16.h>

#define N_NODES 50000
#define N_PAD   50176    // padded rows for GEMM staging (multiple of 128)
#define N_EDGES 800000
#define IN_FEAT 256
#define HEADS 8
#define D_K 64
#define HD 512  // HEADS*D_K

typedef __hip_bfloat16 bf16;
typedef unsigned int u32;

using bf16x8 = __attribute__((ext_vector_type(8))) short;
using f32x4  = __attribute__((ext_vector_type(4))) float;

// ---------------- workspace layout (bytes) ----------------
#define WS_Q       0
#define WS_K       51200000
#define WS_V       102400000
#define WS_OFFSETS 153600000
#define WS_CURSOR  153800192
#define WS_DEG     154000192
#define WS_CSR     154200192
#define WS_SQ2     157400192
#define WS_AUX     159000192   // int[64] scan partials

// d_out used as scratch before edge_attn overwrites it entirely:
#define DOUT_XB 0
#define DOUT_WT 25690112

#define SCAN_BLOCKS 49   // ceil(50000/1024)

__device__ __forceinline__ float bflo(u32 u) { return __uint_as_float(u << 16); }
__device__ __forceinline__ float bfhi(u32 u) { return __uint_as_float(u & 0xffff0000u); }

__device__ __forceinline__ void gload16(const void* g, void* l)
{
    __builtin_amdgcn_global_load_lds(
        (const __attribute__((address_space(1))) unsigned int*)g,
        (__attribute__((address_space(3))) unsigned int*)l,
        16, 0, 0);
}

// ---------------- input conversion ----------------
__global__ __launch_bounds__(256) void convert_x(
    const float* __restrict__ x, bf16* __restrict__ xb)
{
    const int t   = blockIdx.x * 256 + threadIdx.x;
    const int row = t >> 5;
    const int c8  = (t & 31) * 8;
    if (row >= N_PAD) return;
    alignas(16) bf16 tmp[8];
    if (row < N_NODES) {
        const float* p = x + (size_t)row * IN_FEAT + c8;
        float4 a = *(const float4*)p;
        float4 b = *(const float4*)(p + 4);
        tmp[0] = __float2bfloat16(a.x); tmp[1] = __float2bfloat16(a.y);
        tmp[2] = __float2bfloat16(a.z); tmp[3] = __float2bfloat16(a.w);
        tmp[4] = __float2bfloat16(b.x); tmp[5] = __float2bfloat16(b.y);
        tmp[6] = __float2bfloat16(b.z); tmp[7] = __float2bfloat16(b.w);
    } else {
#pragma unroll
        for (int i = 0; i < 8; ++i) tmp[i] = __float2bfloat16(0.f);
    }
    *(uint4*)(xb + (size_t)row * IN_FEAT + c8) = *(const uint4*)tmp;
}

__global__ __launch_bounds__(256) void convert_w(
    const float* __restrict__ Wq, const float* __restrict__ Wk, const float* __restrict__ Wv,
    bf16* __restrict__ Wt)
{
    const int t = blockIdx.x * 256 + threadIdx.x;
    if (t >= 3 * 512 * 256) return;
    const int mat = t >> 17;
    const int r   = t & 131071;
    const int n   = r >> 8;
    const int k   = r & 255;
    const float* W = (mat == 0) ? Wq : (mat == 1) ? Wk : Wv;
    Wt[t] = __float2bfloat16(W[k * HD + n]);
}

// ---------------- MFMA bf16 QKV GEMM: double-buffered pipeline ----------------
__global__ __launch_bounds__(256) void mfma_qkv(
    const bf16* __restrict__ xb, const bf16* __restrict__ Wt,
    bf16* __restrict__ Qb, bf16* __restrict__ Kb, bf16* __restrict__ Vb)
{
    __shared__ uint4 lds4[2048];   // 32 KiB: [buf][A 8K | B 8K]
    char* lds = (char*)lds4;

    const int tid  = threadIdx.x;
    const int lane = tid & 63;
    const int wid  = tid >> 6;
    const int wr   = wid >> 1;
    const int wc   = wid & 1;

    const int m0  = blockIdx.x * 128;
    const int n0  = blockIdx.y * 128;
    const int mat = blockIdx.z;
    const bf16* __restrict__ wt = Wt + (size_t)mat * 512 * 256;
    bf16* __restrict__ outp = (mat == 0) ? Qb : (mat == 1) ? Kb : Vb;

    const int rch  = lane >> 2;
    const int slot = (lane & 3) ^ (rch & 3);
    const int sc0  = wid;
    const int sc1  = wid + 4;
    const size_t arow0 = (size_t)(m0 + sc0 * 16 + rch) * IN_FEAT + slot * 8;
    const size_t arow1 = (size_t)(m0 + sc1 * 16 + rch) * IN_FEAT + slot * 8;
    const size_t brow0 = (size_t)(n0 + sc0 * 16 + rch) * IN_FEAT + slot * 8;
    const size_t brow1 = (size_t)(n0 + sc1 * 16 + rch) * IN_FEAT + slot * 8;

    const int fr    = lane & 15;
    const int fslot = (((lane >> 4) ^ (lane & 3)) << 4);
    const int abase = (wr * 64 + fr) * 64 + fslot;
    const int bbase = (wc * 64 + fr) * 64 + fslot;

    f32x4 acc[4][4];
#pragma unroll
    for (int i = 0; i < 4; ++i)
#pragma unroll
        for (int j = 0; j < 4; ++j) acc[i][j] = {0.f, 0.f, 0.f, 0.f};

#define STAGE(t, buf) do {                                              \
        gload16(xb + arow0 + (t) * 32, lds + (buf) * 16384 + sc0 * 1024);          \
        gload16(xb + arow1 + (t) * 32, lds + (buf) * 16384 + sc1 * 1024);          \
        gload16(wt + brow0 + (t) * 32, lds + (buf) * 16384 + 8192 + sc0 * 1024);   \
        gload16(wt + brow1 + (t) * 32, lds + (buf) * 16384 + 8192 + sc1 * 1024);   \
    } while (0)

    STAGE(0, 0);
#pragma unroll
    for (int t = 0; t < 8; ++t) {
        const int cur = t & 1;
        if (t < 7) {
            STAGE(t + 1, cur ^ 1);
            asm volatile("s_waitcnt vmcnt(4)" ::: "memory");   // tile t landed (mine)
        } else {
            asm volatile("s_waitcnt vmcnt(0)" ::: "memory");
        }
        __builtin_amdgcn_s_barrier();                          // tile t landed (all waves)

        const char* A = lds + cur * 16384;
        const char* B = A + 8192;
        bf16x8 aF[4], bF[4];
#pragma unroll
        for (int m = 0; m < 4; ++m) aF[m] = *(const bf16x8*)(A + abase + m * 1024);
#pragma unroll
        for (int n = 0; n < 4; ++n) bF[n] = *(const bf16x8*)(B + bbase + n * 1024);
#pragma unroll
        for (int m = 0; m < 4; ++m)
#pragma unroll
            for (int n = 0; n < 4; ++n)
                acc[m][n] = __builtin_amdgcn_mfma_f32_16x16x32_bf16(aF[m], bF[n], acc[m][n], 0, 0, 0);
        __builtin_amdgcn_s_barrier();                          // reads done before overwrite
    }
#undef STAGE

    const int c_col = lane & 15;
    const int r_hi  = (lane >> 4) * 4;
#pragma unroll
    for (int m = 0; m < 4; ++m) {
        const int grow_base = m0 + wr * 64 + m * 16 + r_hi;
#pragma unroll
        for (int j = 0; j < 4; ++j) {
            const int grow = grow_base + j;
            if (grow < N_NODES) {
#pragma unroll
                for (int n = 0; n < 4; ++n)
                    outp[(size_t)grow * HD + n0 + wc * 64 + n * 16 + c_col] =
                        __float2bfloat16(acc[m][n][j]);
            }
        }
    }
}

// ---------------- CSR build ----------------
__global__ void hist_kernel(const int* __restrict__ row, int* __restrict__ deg)
{
    int e = blockIdx.x * 256 + threadIdx.x;
    if (e < N_EDGES) atomicAdd(&deg[row[e]], 1);
}

__global__ __launch_bounds__(1024) void scan_local(const int* __restrict__ deg,
                                                   int* __restrict__ offsets,
                                                   int* __restrict__ aux)
{
    __shared__ int buf[1024];
    const int tid = threadIdx.x;
    const int i = blockIdx.x * 1024 + tid;
    const int v = (i < N_NODES) ? deg[i] : 0;
    buf[tid] = v;
    __syncthreads();
    for (int off = 1; off < 1024; off <<= 1) {
        int t = (tid >= off) ? buf[tid - off] : 0;
        __syncthreads();
        buf[tid] += t;
        __syncthreads();
    }
    if (i < N_NODES) offsets[i] = buf[tid] - v;
    if (tid == 1023) aux[blockIdx.x] = buf[1023];
}

__global__ void scan_aux(int* __restrict__ aux)
{
    const int tid = threadIdx.x;
    const int orig = (tid < SCAN_BLOCKS) ? aux[tid] : 0;
    int v = orig;
    for (int off = 1; off < 64; off <<= 1) {
        int t = __shfl_up(v, off, 64);
        if (tid >= off) v += t;
    }
    if (tid < SCAN_BLOCKS) aux[tid] = v - orig;
}

__global__ __launch_bounds__(1024) void scan_apply(const int* __restrict__ aux,
                                                   int* __restrict__ offsets,
                                                   int* __restrict__ cursor)
{
    const int i = blockIdx.x * 1024 + threadIdx.x;
    if (i < N_NODES) {
        const int off = offsets[i] + aux[i >> 10];
        offsets[i] = off;
        cursor[i]  = off;
    }
    if (i == 0) offsets[N_NODES] = N_EDGES;
}

__global__ void scatter_kernel(const int* __restrict__ row, const int* __restrict__ col,
                               int* __restrict__ cursor, int* __restrict__ csr_col)
{
    int e = blockIdx.x * 256 + threadIdx.x;
    if (e < N_EDGES) {
        const int pos = atomicAdd(&cursor[row[e]], 1);
        csr_col[pos] = col[e];
    }
}

// ---------------- sQ2 precompute ----------------
__global__ __launch_bounds__(256) void sq2_kernel(
    const bf16* __restrict__ Qb, const float* __restrict__ Dm, float* __restrict__ sQ2)
{
    const int lane = threadIdx.x & 63;
    const int wid  = threadIdx.x >> 6;
    const int n = blockIdx.x * 4 + wid;
    if (n >= N_NODES) return;

    uint4 qp = *(const uint4*)(Qb + (size_t)n * HD + lane * 8);
    float4 da = *(const float4*)(Dm + lane * 8);
    float4 db = *(const float4*)(Dm + lane * 8 + 4);
    float q0 = bflo(qp.x), q1 = bfhi(qp.x), q2 = bflo(qp.y), q3 = bfhi(qp.y);
    float q4 = bflo(qp.z), q5 = bfhi(qp.z), q6 = bflo(qp.w), q7 = bfhi(qp.w);
    float s = da.x*q0*q0 + da.y*q1*q1 + da.z*q2*q2 + da.w*q3*q3
            + db.x*q4*q4 + db.y*q5*q5 + db.z*q6*q6 + db.w*q7*q7;
    s += __shfl_xor(s, 1, 64);
    s += __shfl_xor(s, 2, 64);
    s += __shfl_xor(s, 4, 64);
    if ((lane & 7) == 0) sQ2[n * 8 + (lane >> 3)] = s;
}

// ---------------- fused edge phase: R9 best config (64-thread blocks) --------
// One 64-thread block per node (50000 blocks, hardware backfill). Measured
// best: 254 us, 3.84 TB/s gather BW (= path saturation; R10's 2-wave variant
// regressed: occ 43->30%, BW 3.84->3.50). Phase A: lane = (edge jA, head hA),
// per-lane direct 8x16B Q loads + within-lane dot vs float DK in LDS.
// Batched 6-shuffle online softmax. Phase B: coalesced direct V loads.
__global__ __launch_bounds__(64) void edge_attn(
    const bf16* __restrict__ Qb, const bf16* __restrict__ Kb, const bf16* __restrict__ Vb,
    const float* __restrict__ Dm, const float* __restrict__ sQ2,
    const int* __restrict__ offsets, const int* __restrict__ csr_col,
    float* __restrict__ out)
{
    __shared__ float dk_lds[8][72];   // [head][64 dims + pad] = 2.25 KiB

    const int lane = threadIdx.x;     // 0..63
    const int r = blockIdx.x;

    const int hB = lane >> 3;         // B-layout: head of dims [lane*8, +8)
    const int tB = lane & 7;
    const int hA = lane & 7;          // A-layout: head
    const int jA = lane >> 3;         // A-layout: edge slot

    const float4 da = *(const float4*)(Dm + lane * 8);
    const float4 db = *(const float4*)(Dm + lane * 8 + 4);

    // ---- node init: DK = D*K[r] into LDS (B-layout), sK2 per head ----
    uint4 kp = *(const uint4*)(Kb + (size_t)r * HD + lane * 8);
    const float k0 = bflo(kp.x), k1 = bfhi(kp.x), k2 = bflo(kp.y), k3 = bfhi(kp.y);
    const float k4 = bflo(kp.z), k5 = bfhi(kp.z), k6 = bflo(kp.w), k7 = bfhi(kp.w);
    const float e0 = da.x*k0, e1 = da.y*k1, e2 = da.z*k2, e3 = da.w*k3;
    const float e4 = db.x*k4, e5 = db.y*k5, e6 = db.z*k6, e7 = db.w*k7;
    float sk = e0*k0 + e1*k1 + e2*k2 + e3*k3 + e4*k4 + e5*k5 + e6*k6 + e7*k7;
    sk += __shfl_xor(sk, 1, 64);
    sk += __shfl_xor(sk, 2, 64);
    sk += __shfl_xor(sk, 4, 64);      // sK2 for head hB on every lane
    {
        float4 w0 = {e0, e1, e2, e3}, w1 = {e4, e5, e6, e7};
        *(float4*)&dk_lds[hB][tB * 8]     = w0;
        *(float4*)&dk_lds[hB][tB * 8 + 4] = w1;
    }
    const float skA = __shfl(sk, hA * 8, 64);   // sK2 for A-head

    const int s0 = offsets[r];
    const int s1 = offsets[r + 1];

    float m = -INFINITY, l = 0.f;
    float o0=0,o1=0,o2=0,o3=0,o4=0,o5=0,o6=0,o7=0;

    const float* dkrow = &dk_lds[hA][0];

    for (int eb = s0; eb < s1; eb += 8) {
        const int cnt = min(8, s1 - eb);              // wave-uniform
        const int cj  = csr_col[eb + min(jA, cnt - 1)];

        // ---- phase A: per-lane direct Q loads + within-lane dot ----
        const bf16* qrow = Qb + (size_t)cj * HD + hA * D_K;
        float cross = 0.f;
#pragma unroll
        for (int t = 0; t < 8; ++t) {
            uint4 qp2 = *(const uint4*)(qrow + t * 8);
            float4 ka  = *(const float4*)(dkrow + t * 8);
            float4 kb2 = *(const float4*)(dkrow + t * 8 + 4);
            cross += ka.x * bflo(qp2.x) + ka.y * bfhi(qp2.x)
                   + ka.z * bflo(qp2.y) + ka.w * bfhi(qp2.y)
                   + kb2.x * bflo(qp2.z) + kb2.y * bfhi(qp2.z)
                   + kb2.z * bflo(qp2.w) + kb2.w * bfhi(qp2.w);
        }
        const float sq2v = sQ2[cj * 8 + hA];
        const float sraw = (cj == r) ? cross : (skA - 2.f * cross + sq2v);
        const float y = sraw * 0.125f;
        float s = fmaxf(y, 0.2f * y);                 // leaky_relu 0.2
        if (jA >= cnt) s = -INFINITY;

        // ---- batched online softmax ----
        float bm = s;
        bm = fmaxf(bm, __shfl_xor(bm, 8, 64));
        bm = fmaxf(bm, __shfl_xor(bm, 16, 64));
        bm = fmaxf(bm, __shfl_xor(bm, 32, 64));
        const float mn   = fmaxf(m, bm);
        const float corr = __expf(m - mn);            // exp(-inf)=0 on first pass
        const float w    = __expf(s - mn);
        m = mn;
        float ls = w;
        ls += __shfl_xor(ls, 8, 64);
        ls += __shfl_xor(ls, 16, 64);
        ls += __shfl_xor(ls, 32, 64);
        l = l * corr + ls;

        // ---- phase B: coalesced V accumulation ----
        const float corrB = __shfl(corr, hB, 64);
        o0*=corrB; o1*=corrB; o2*=corrB; o3*=corrB;
        o4*=corrB; o5*=corrB; o6*=corrB; o7*=corrB;
#pragma unroll
        for (int e = 0; e < 8; ++e) {
            if (e >= cnt) break;                      // wave-uniform
            const int   ce    = __shfl(cj, e * 8, 64);
            const float alpha = __shfl(w, e * 8 + hB, 64);
            uint4 vp = *(const uint4*)(Vb + (size_t)ce * HD + lane * 8);
            o0 = fmaf(alpha, bflo(vp.x), o0);
            o1 = fmaf(alpha, bfhi(vp.x), o1);
            o2 = fmaf(alpha, bflo(vp.y), o2);
            o3 = fmaf(alpha, bfhi(vp.y), o3);
            o4 = fmaf(alpha, bflo(vp.z), o4);
            o5 = fmaf(alpha, bfhi(vp.z), o5);
            o6 = fmaf(alpha, bflo(vp.w), o6);
            o7 = fmaf(alpha, bfhi(vp.w), o7);
        }
    }

    const float lB  = __shfl(l, hB, 64);
    const float inv = 1.f / (lB + 1e-16f);
    float4 r0 = {o0*inv, o1*inv, o2*inv, o3*inv};
    float4 r1 = {o4*inv, o5*inv, o6*inv, o7*inv};
    *(float4*)(out + (size_t)r * HD + lane * 8)     = r0;
    *(float4*)(out + (size_t)r * HD + lane * 8 + 4) = r1;
}

// ---------------- launcher ----------------
extern "C" void kernel_launch(void* const* d_in, const int* in_sizes, int n_in,
                              void* d_out, int out_size, void* d_ws, size_t ws_size,
                              hipStream_t stream)
{
    const float* x  = (const float*)d_in[0];
    const int*   ei = (const int*)d_in[1];
    const float* Wq = (const float*)d_in[2];
    const float* Wk = (const float*)d_in[3];
    const float* Wv = (const float*)d_in[4];
    const float* Dm = (const float*)d_in[5];
    float* out = (float*)d_out;

    char* ws = (char*)d_ws;
    bf16* Qb      = (bf16*)(ws + WS_Q);
    bf16* Kb      = (bf16*)(ws + WS_K);
    bf16* Vb      = (bf16*)(ws + WS_V);
    int*  offsets = (int*)(ws + WS_OFFSETS);
    int*  cursor  = (int*)(ws + WS_CURSOR);
    int*  deg     = (int*)(ws + WS_DEG);
    int*  csr_col = (int*)(ws + WS_CSR);
    float* sQ2    = (float*)(ws + WS_SQ2);
    int*  aux     = (int*)(ws + WS_AUX);

    bf16* xb = (bf16*)((char*)d_out + DOUT_XB);
    bf16* Wt = (bf16*)((char*)d_out + DOUT_WT);

    const int* row = ei;
    const int* col = ei + N_EDGES;

    hipMemsetAsync(deg, 0, N_NODES * sizeof(int), stream);
    hipLaunchKernelGGL(convert_x, dim3(N_PAD * 32 / 256), dim3(256), 0, stream, x, xb);
    hipLaunchKernelGGL(convert_w, dim3((3 * 512 * 256 + 255) / 256), dim3(256), 0, stream,
                       Wq, Wk, Wv, Wt);
    hipLaunchKernelGGL(hist_kernel, dim3((N_EDGES + 255) / 256), dim3(256), 0, stream, row, deg);
    hipLaunchKernelGGL(mfma_qkv, dim3(N_PAD / 128, 4, 3), dim3(256), 0, stream,
                       xb, Wt, Qb, Kb, Vb);
    hipLaunchKernelGGL(scan_local, dim3(SCAN_BLOCKS), dim3(1024), 0, stream, deg, offsets, aux);
    hipLaunchKernelGGL(scan_aux, dim3(1), dim3(64), 0, stream, aux);
    hipLaunchKernelGGL(scan_apply, dim3(SCAN_BLOCKS), dim3(1024), 0, stream, aux, offsets, cursor);
    hipLaunchKernelGGL(scatter_kernel, dim3((N_EDGES + 255) / 256), dim3(256), 0, stream,
                       row, col, cursor, csr_col);
    hipLaunchKernelGGL(sq2_kernel, dim3((N_NODES + 3) / 4), dim3(256), 0, stream, Qb, Dm, sQ2);
    hipLaunchKernelGGL(edge_attn, dim3(N_NODES), dim3(64), 0, stream,
                       Qb, Kb, Vb, Dm, sQ2, offsets, csr_col, out);
}